// Round 4
// baseline (570.609 us; speedup 1.0000x reference)
//
#include <hip/hip_runtime.h>
#include <cfloat>

#define TOKENS 16384   // B*N
#define DDIM   2048
#define NEXP   128
#define KTOP   8
#define MB     32      // tokens per block
#define KB     32      // k per LDS tile
#define NTILES (DDIM / KB)   // 64

// branchless sorted-insert into descending top-8 list.
// strict '>' => ties keep the earlier (lower) index, matching jax.lax.top_k.
__device__ __forceinline__ void insert8(float (&vals)[8], int (&idxs)[8], float v, int e) {
    bool c[8];
#pragma unroll
    for (int p = 0; p < 8; ++p) c[p] = v > vals[p];
#pragma unroll
    for (int p = 7; p >= 1; --p) {
        vals[p] = c[p] ? (c[p - 1] ? vals[p - 1] : v) : vals[p];
        idxs[p] = c[p] ? (c[p - 1] ? idxs[p - 1] : e) : idxs[p];
    }
    vals[0] = c[0] ? v : vals[0];
    idxs[0] = c[0] ? e : idxs[0];
}

// K-loop thread layout: ec = tid&63 -> experts {ec, ec+64}   (TN=2, from LDS)
//                       tr = tid>>6 -> tokens  {tr+4i, i<8}  (TM=8, x direct from
//                       global; address wave-uniform -> HW dedups to a broadcast).
// LDS holds ONLY W tiles (double-buffered, XOR float4-slot swizzle).
// LDS traffic/FLOP = 2/TM = 0.25 B/FLOP < 0.33 balance point -> VALU-bound.
// grid = 512 -> 2 blocks/CU -> 2 waves/SIMD for latency hiding.
__global__ __launch_bounds__(256, 1) void router_kernel(
    const float* __restrict__ x, const float* __restrict__ W,
    const float* __restrict__ b, float* __restrict__ out_gates,
    float* __restrict__ out_idx)
{
    // 33280 B LDS: W-tiles (32 KB) overlaid with epilogue scratch (33.3 KB)
    __shared__ __align__(16) char smem[33280];
    float* ws0 = (float*)smem;                // [2][128*32] = 32768 B (GEMM phase)
    float* lg  = (float*)smem;                // [32][132]   = 16896 B (epilogue)
    float* plv = (float*)(smem + 16896);      // [256][8] f32 = 8192 B
    int*   pli = (int*)(smem + 25088);        // [256][8] i32 = 8192 B

    const int tid  = threadIdx.x;
    const int ec   = tid & 63;          // expert column
    const int tr   = tid >> 6;          // token row group (0..3)
    const int tok0 = blockIdx.x * MB;

    float bv[2];
    bv[0] = b[ec];
    bv[1] = b[ec + 64];

    float acc[8][2];
#pragma unroll
    for (int i = 0; i < 8; ++i) { acc[i][0] = 0.0f; acc[i][1] = 0.0f; }

    const float4* x4 = (const float4*)x;
    const float4* W4 = (const float4*)W;

    // x row pointers: tokens tr+4i; address is uniform across the 64 ec-lanes
    const float4* xp[8];
#pragma unroll
    for (int i = 0; i < 8; ++i)
        xp[i] = x4 + (size_t)(tok0 + tr + 4 * i) * (DDIM / 4);

    // W staging: rows e = 32r + (tid>>3), float4 slot q = tid&7,
    // XOR-swizzled store slot = q ^ (e&7)
    const int wrow = tid >> 3, wq = tid & 7;
    size_t wsrc[4]; int wdst[4];
#pragma unroll
    for (int r = 0; r < 4; ++r) {
        int e = 32 * r + wrow;
        wsrc[r] = (size_t)e * (DDIM / 4) + wq;
        wdst[r] = e * KB + 4 * (wq ^ (e & 7));
    }

    float4 sw[4];

    // ---- prologue: stage W tile 0 ----
#pragma unroll
    for (int r = 0; r < 4; ++r) sw[r] = W4[wsrc[r]];
#pragma unroll
    for (int r = 0; r < 4; ++r) *(float4*)&ws0[wdst[r]] = sw[r];
    __syncthreads();

    // ---- main K loop ----
    for (int t = 0; t < NTILES; ++t) {
        const float* wsc = ws0 + (t & 1) * (NEXP * KB);
        const bool more = (t + 1) < NTILES;
        if (more) {
#pragma unroll
            for (int r = 0; r < 4; ++r) sw[r] = W4[wsrc[r] + (t + 1) * 8];
        }

        const int kq0 = t * 8;
#pragma unroll
        for (int kq = 0; kq < 8; ++kq) {
            float4 xv[8], wv[2];
#pragma unroll
            for (int i = 0; i < 8; ++i) xv[i] = xp[i][kq0 + kq];
            // e&7 == ec&7 for both experts (64 ≡ 0 mod 8)
            wv[0] = *(const float4*)&wsc[ec * KB + 4 * (kq ^ (ec & 7))];
            wv[1] = *(const float4*)&wsc[(ec + 64) * KB + 4 * (kq ^ (ec & 7))];
            // strictly k-ascending (t, kq, x/y/z/w) -> bit-identical to R0/R2
#pragma unroll
            for (int i = 0; i < 8; ++i)
#pragma unroll
                for (int j = 0; j < 2; ++j) {
                    acc[i][j] += xv[i].x * wv[j].x;
                    acc[i][j] += xv[i].y * wv[j].y;
                    acc[i][j] += xv[i].z * wv[j].z;
                    acc[i][j] += xv[i].w * wv[j].w;
                }
        }

        if (more) {
            float* wsn = ws0 + ((t + 1) & 1) * (NEXP * KB);
#pragma unroll
            for (int r = 0; r < 4; ++r) *(float4*)&wsn[wdst[r]] = sw[r];
        }
        __syncthreads();
    }

    // ---- epilogue: logits -> LDS (overlay; W tiles dead after final barrier) ----
#pragma unroll
    for (int i = 0; i < 8; ++i) {
        int m = tr + 4 * i;
        lg[m * 132 + ec]      = acc[i][0] + bv[0];
        lg[m * 132 + ec + 64] = acc[i][1] + bv[1];
    }
    __syncthreads();

    // ---- partial top-8: 8 threads per token, 16 experts each ----
    {
        int tt = tid >> 3, p = tid & 7;
        float vals[8]; int idxs[8];
#pragma unroll
        for (int k = 0; k < 8; ++k) { vals[k] = -FLT_MAX; idxs[k] = 0; }
        const float* row = &lg[tt * 132 + p * 16];
#pragma unroll
        for (int q = 0; q < 16; ++q)
            insert8(vals, idxs, row[q], p * 16 + q);
#pragma unroll
        for (int k = 0; k < 8; ++k) {
            plv[tid * 8 + k] = vals[k];
            pli[tid * 8 + k] = idxs[k];
        }
    }
    __syncthreads();

    // ---- merge + softmax + index output (1 thread per token) ----
    float g[8]; int fidx[8];
    const bool active = (tid < MB);
    if (active) {
        float vals[8]; int idxs[8];
#pragma unroll
        for (int k = 0; k < 8; ++k) { vals[k] = -FLT_MAX; idxs[k] = 0; }
        for (int p = 0; p < 8; ++p) {
#pragma unroll
            for (int k = 0; k < 8; ++k)
                insert8(vals, idxs, plv[(tid * 8 + p) * 8 + k], pli[(tid * 8 + p) * 8 + k]);
        }
        float mx = vals[0];
        float s = 0.0f;
#pragma unroll
        for (int k = 0; k < 8; ++k) { g[k] = __expf(vals[k] - mx); s += g[k]; }
        float inv = 1.0f / s;
#pragma unroll
        for (int k = 0; k < 8; ++k) { g[k] *= inv; fidx[k] = idxs[k]; }
        // indices written as float values (whole out buffer is read back as f32)
#pragma unroll
        for (int k = 0; k < 8; ++k)
            out_idx[(size_t)(tok0 + tid) * KTOP + k] = (float)idxs[k];
    }
    // zero dense gate rows (merge no longer reads lg)
    for (int f = tid; f < MB * 132; f += 256) lg[f] = 0.0f;
    __syncthreads();

    if (active) {
#pragma unroll
        for (int k = 0; k < 8; ++k) lg[tid * 132 + fidx[k]] = g[k];
    }
    __syncthreads();

    // ---- coalesced dense copy-out ----
    for (int f = tid; f < MB * (NEXP / 4); f += 256) {
        int m = f >> 5, e4 = f & 31;
        float4 v = *(const float4*)&lg[m * 132 + e4 * 4];
        ((float4*)out_gates)[(size_t)(tok0 + m) * (NEXP / 4) + e4] = v;
    }
}

extern "C" void kernel_launch(void* const* d_in, const int* in_sizes, int n_in,
                              void* d_out, int out_size, void* d_ws, size_t ws_size,
                              hipStream_t stream) {
    const float* x = (const float*)d_in[0];   // [B,N,D] f32
    const float* W = (const float*)d_in[1];   // [E,D]   f32
    const float* b = (const float*)d_in[2];   // [E]     f32

    float* out_gates = (float*)d_out;                       // [B,N,E] f32
    float* out_idx   = out_gates + (size_t)TOKENS * NEXP;   // [B,N,K] as f32

    dim3 grid(TOKENS / MB);   // 512 blocks = 2 per CU
    dim3 block(256);
    router_kernel<<<grid, block, 0, stream>>>(x, W, b, out_gates, out_idx);
}

// Round 5
// 297.900 us; speedup vs baseline: 1.9154x; 1.9154x over previous
//
#include <hip/hip_runtime.h>
#include <cfloat>

#define TOKENS 16384   // B*N
#define DDIM   2048
#define NEXP   128
#define KTOP   8
#define MB     64      // tokens per block
#define KB     32      // k per LDS tile
#define NTILES (DDIM / KB)   // 64

// branchless sorted-insert into descending top-8 list.
// strict '>' => ties keep the earlier (lower) index, matching jax.lax.top_k.
__device__ __forceinline__ void insert8(float (&vals)[8], int (&idxs)[8], float v, int e) {
    bool c[8];
#pragma unroll
    for (int p = 0; p < 8; ++p) c[p] = v > vals[p];
#pragma unroll
    for (int p = 7; p >= 1; --p) {
        vals[p] = c[p] ? (c[p - 1] ? vals[p - 1] : v) : vals[p];
        idxs[p] = c[p] ? (c[p - 1] ? idxs[p - 1] : e) : idxs[p];
    }
    vals[0] = c[0] ? v : vals[0];
    idxs[0] = c[0] ? e : idxs[0];
}

// R0 structure (proven 282us, exact indices) + two deltas:
//  (1) cross-kq operand double-buffer: ds_reads for kq+1 issue BEFORE the FMA
//      block of kq, hiding the ~150cy LDS read train under 256cy of v_fmac
//      (R0 stalled on lgkmcnt(0) every kq: VALUBusy 40%, LDS 44% -> neither
//      pipe saturated = latency-exposed at 1 wave/SIMD).
//  (2) epilogue LDS overlaid on GEMM tiles: 124KB -> 50KB.
// Accumulation order per output unchanged: (t, kq, x/y/z/w) ascending ->
// bit-identical logits to R0 -> identical top-k indices.
__global__ __launch_bounds__(256, 1) void router_kernel(
    const float* __restrict__ x, const float* __restrict__ W,
    const float* __restrict__ b, float* __restrict__ out_gates,
    float* __restrict__ out_idx)
{
    __shared__ __align__(16) char smem[50176];
    float* xs0 = (float*)smem;                // [2][64*32]  = 16384 B (GEMM)
    float* ws0 = (float*)(smem + 16384);      // [2][128*32] = 32768 B (GEMM)
    float* lg  = (float*)smem;                // [64][132]   = 33792 B (epilogue overlay)
    float* plv = (float*)(smem + 33792);      // [256][8] f32 = 8192 B
    int*   pli = (int*)(smem + 41984);        // [256][8] i32 = 8192 B

    const int tid  = threadIdx.x;
    const int w    = tid >> 6;
    const int lane = tid & 63;
    const int eg   = lane & 15;          // expert group 0..15
    const int tg   = lane >> 4;          // token group within wave 0..3
    const int tgg  = w * 4 + tg;         // global token group 0..15
    const int tok0 = blockIdx.x * MB;

    float bv[8];
#pragma unroll
    for (int j = 0; j < 8; ++j) bv[j] = b[eg + 16 * j];

    float acc[4][8];
#pragma unroll
    for (int i = 0; i < 4; ++i)
#pragma unroll
        for (int j = 0; j < 8; ++j) acc[i][j] = 0.0f;

    const float4* x4 = (const float4*)x;
    const float4* W4 = (const float4*)W;

    // staging assignments (2 x-float4 + 4 W-float4 per thread)
    const int sm0 = (0 * 256 + tid) >> 3, sq0 = tid & 7;
    const int sm1 = (1 * 256 + tid) >> 3;
    float4 sx[2], sw[4];

    // ---- prologue: stage tile 0 ----
    sx[0] = x4[(size_t)(tok0 + sm0) * (DDIM / 4) + sq0];
    sx[1] = x4[(size_t)(tok0 + sm1) * (DDIM / 4) + sq0];
#pragma unroll
    for (int r = 0; r < 4; ++r) {
        int e = (r * 256 + tid) >> 3;
        sw[r] = W4[(size_t)e * (DDIM / 4) + sq0];
    }
    *(float4*)&xs0[sm0 * KB + 4 * (sq0 ^ (sm0 & 7))] = sx[0];
    *(float4*)&xs0[sm1 * KB + 4 * (sq0 ^ (sm1 & 7))] = sx[1];
#pragma unroll
    for (int r = 0; r < 4; ++r) {
        int e = (r * 256 + tid) >> 3;
        *(float4*)&ws0[e * KB + 4 * (sq0 ^ (e & 7))] = sw[r];
    }
    __syncthreads();

    // ---- main K loop ----
    for (int t = 0; t < NTILES; ++t) {
        const float* xsc = xs0 + (t & 1) * (MB * KB);
        const float* wsc = ws0 + (t & 1) * (NEXP * KB);
        const bool more = (t + 1) < NTILES;
        if (more) {
            const int kq0 = (t + 1) * (KB / 4);
            sx[0] = x4[(size_t)(tok0 + sm0) * (DDIM / 4) + kq0 + sq0];
            sx[1] = x4[(size_t)(tok0 + sm1) * (DDIM / 4) + kq0 + sq0];
#pragma unroll
            for (int r = 0; r < 4; ++r) {
                int e = (r * 256 + tid) >> 3;
                sw[r] = W4[(size_t)e * (DDIM / 4) + kq0 + sq0];
            }
        }

        // operand double-buffer across kq (all indices static after unroll)
        float4 xv[2][4], wv[2][8];
#pragma unroll
        for (int i = 0; i < 4; ++i) {
            int m = tgg + 16 * i;
            xv[0][i] = *(const float4*)&xsc[m * KB + 4 * (0 ^ (m & 7))];
        }
#pragma unroll
        for (int j = 0; j < 8; ++j) {
            int e = eg + 16 * j;
            wv[0][j] = *(const float4*)&wsc[e * KB + 4 * (0 ^ (e & 7))];
        }

#pragma unroll
        for (int kq = 0; kq < KB / 4; ++kq) {
            const int cb = kq & 1, nb = cb ^ 1;
            if (kq + 1 < KB / 4) {
#pragma unroll
                for (int i = 0; i < 4; ++i) {
                    int m = tgg + 16 * i;
                    xv[nb][i] = *(const float4*)&xsc[m * KB + 4 * ((kq + 1) ^ (m & 7))];
                }
#pragma unroll
                for (int j = 0; j < 8; ++j) {
                    int e = eg + 16 * j;
                    wv[nb][j] = *(const float4*)&wsc[e * KB + 4 * ((kq + 1) ^ (e & 7))];
                }
            }
            // strict k-ascending (t, kq, x/y/z/w) -> bit-identical to R0
#pragma unroll
            for (int i = 0; i < 4; ++i)
#pragma unroll
                for (int j = 0; j < 8; ++j) {
                    acc[i][j] += xv[cb][i].x * wv[cb][j].x;
                    acc[i][j] += xv[cb][i].y * wv[cb][j].y;
                    acc[i][j] += xv[cb][i].z * wv[cb][j].z;
                    acc[i][j] += xv[cb][i].w * wv[cb][j].w;
                }
        }

        if (more) {
            float* xsn = xs0 + ((t + 1) & 1) * (MB * KB);
            float* wsn = ws0 + ((t + 1) & 1) * (NEXP * KB);
            *(float4*)&xsn[sm0 * KB + 4 * (sq0 ^ (sm0 & 7))] = sx[0];
            *(float4*)&xsn[sm1 * KB + 4 * (sq0 ^ (sm1 & 7))] = sx[1];
#pragma unroll
            for (int r = 0; r < 4; ++r) {
                int e = (r * 256 + tid) >> 3;
                *(float4*)&wsn[e * KB + 4 * (sq0 ^ (e & 7))] = sw[r];
            }
        }
        __syncthreads();
    }

    // ---- epilogue: logits -> LDS (overlay; GEMM tiles dead after final barrier) ----
#pragma unroll
    for (int i = 0; i < 4; ++i) {
        int m = tgg + 16 * i;
#pragma unroll
        for (int j = 0; j < 8; ++j)
            lg[m * 132 + eg + 16 * j] = acc[i][j] + bv[j];
    }
    __syncthreads();

    // ---- partial top-8: 4 threads per token, 32 experts each ----
    {
        int tt = tid >> 2, p = tid & 3;
        float vals[8]; int idxs[8];
#pragma unroll
        for (int k = 0; k < 8; ++k) { vals[k] = -FLT_MAX; idxs[k] = 0; }
        const float* row = &lg[tt * 132 + p * 32];
        for (int q = 0; q < 32; ++q)
            insert8(vals, idxs, row[q], p * 32 + q);
#pragma unroll
        for (int k = 0; k < 8; ++k) {
            plv[tid * 8 + k] = vals[k];
            pli[tid * 8 + k] = idxs[k];
        }
    }
    __syncthreads();

    // ---- merge + softmax + index output (1 thread per token) ----
    float g[8]; int fidx[8];
    const bool active = (tid < MB);
    if (active) {
        float vals[8]; int idxs[8];
#pragma unroll
        for (int k = 0; k < 8; ++k) { vals[k] = -FLT_MAX; idxs[k] = 0; }
        for (int p = 0; p < 4; ++p) {
#pragma unroll
            for (int k = 0; k < 8; ++k)
                insert8(vals, idxs, plv[(tid * 4 + p) * 8 + k], pli[(tid * 4 + p) * 8 + k]);
        }
        float mx = vals[0];
        float s = 0.0f;
#pragma unroll
        for (int k = 0; k < 8; ++k) { g[k] = __expf(vals[k] - mx); s += g[k]; }
        float inv = 1.0f / s;
#pragma unroll
        for (int k = 0; k < 8; ++k) { g[k] *= inv; fidx[k] = idxs[k]; }
        // indices written as float values (whole out buffer is read back as f32)
#pragma unroll
        for (int k = 0; k < 8; ++k)
            out_idx[(size_t)(tok0 + tid) * KTOP + k] = (float)idxs[k];
    }
    // zero dense gate rows (merge no longer reads lg)
    for (int f = tid; f < MB * 132; f += 256) lg[f] = 0.0f;
    __syncthreads();

    if (active) {
#pragma unroll
        for (int k = 0; k < 8; ++k) lg[tid * 132 + fidx[k]] = g[k];
    }
    __syncthreads();

    // ---- coalesced dense copy-out ----
    for (int f = tid; f < MB * (NEXP / 4); f += 256) {
        int m = f >> 5, e4 = f & 31;
        float4 v = *(const float4*)&lg[m * 132 + e4 * 4];
        ((float4*)out_gates)[(size_t)(tok0 + m) * (NEXP / 4) + e4] = v;
    }
}

extern "C" void kernel_launch(void* const* d_in, const int* in_sizes, int n_in,
                              void* d_out, int out_size, void* d_ws, size_t ws_size,
                              hipStream_t stream) {
    const float* x = (const float*)d_in[0];   // [B,N,D] f32
    const float* W = (const float*)d_in[1];   // [E,D]   f32
    const float* b = (const float*)d_in[2];   // [E]     f32

    float* out_gates = (float*)d_out;                       // [B,N,E] f32
    float* out_idx   = out_gates + (size_t)TOKENS * NEXP;   // [B,N,K] as f32

    dim3 grid(TOKENS / MB);   // 256 blocks
    dim3 block(256);
    router_kernel<<<grid, block, 0, stream>>>(x, W, b, out_gates, out_idx);
}